// Round 18
// baseline (134.765 us; speedup 1.0000x reference)
//
#include <hip/hip_runtime.h>
#include <hip/hip_bf16.h>
#include <math.h>
#include <stdint.h>

// Round 18: h rematerialized as f16 swizzled images by a FAST prep (packed
// v_pk_fma_f16 AGEN, W1 LDS-staged), and the GEMM becomes a pure-load MFMA
// machine: no LDS, no barriers, no VALU-gen; A and B frags both direct
// global->VGPR from prebaked swizzled images. 512thr / 8 waves (2Mx4N),
// wave tile 64x48 (acc 48), ~124 VGPR, launch_bounds(512,4) -> 2 blk/CU
// = 4 waves/SIMD. 2-deep register double-buffer. XCD-coherent mapping.

typedef __bf16 bf16_t;
typedef __attribute__((ext_vector_type(8))) __bf16 bf16x8;
typedef __attribute__((ext_vector_type(8))) _Float16 f16x8;
typedef __attribute__((ext_vector_type(2))) _Float16 f16x2;
typedef __attribute__((ext_vector_type(4))) float f32x4;

#define M_TOT 16384
#define E_DIM 768
#define F_DIM 3072

constexpr int BM = 128, BN = 128, BK = 64;   // legacy (fallback only)
constexpr int MT = M_TOT / BM;    // 128 (also A-panel count)
constexpr int NT = E_DIM / BN;    // fallback
constexpr int KT = F_DIM / BK;    // 48
constexpr int KT2 = 2 * KT;       // 96 k-steps (K=32)
constexpr int ATILE = 8192;       // 128x32 f16 A tile image bytes
constexpr int BTILE = 12288;      // 192x32 f16 B tile image bytes
constexpr int NT4 = 4;            // 192-col B panels

// ws layout
constexpr size_t WS_A    = 0;                                    // 128*96*8192
constexpr size_t WS_B    = WS_A + (size_t)MT * KT2 * ATILE;      // 100,663,296
constexpr size_t WS_NEED = WS_B + (size_t)NT4 * KT2 * BTILE;     // 105,381,888

// --------------------------------------------------- prep (h + W2) ----
// blocks 0..767: h images, block (mt, seg) covers kt = seg*8..seg*8+7.
// blocks 768..959: W2 192-col swizzled f16 tile images (r15-proven).
__global__ __launch_bounds__(256)
void ffq_prep(const float* __restrict__ x, const float* __restrict__ theta,
              const float* __restrict__ W1, const float* __restrict__ b1,
              const float* __restrict__ W2, char* __restrict__ ws)
{
    const int t = threadIdx.x;
    const int bid = blockIdx.x;

    if (bid < MT * 6) {
        // ---- h: packed-f16 AGEN from LDS W1 slice ----
        __shared__ __align__(16) uint32_t W1loc[256][4];  // [kpl][q] f16 pairs, 4KB
        __shared__ uint32_t b1loc[256];                   // 1KB
        __shared__ __align__(16) char Hsm[16384];         // 2 x 8KB images

        const int mt = bid / 6, seg = bid % 6;
        const int row = t & 127, half = t >> 7;

        // fill W1/b1 LDS slice: global kp = seg*256 + t
        {
            const int kp = seg * 256 + t;
            #pragma unroll
            for (int q = 0; q < 4; ++q) {
                const float2 a = *reinterpret_cast<const float2*>(
                    &W1[(size_t)q * F_DIM + 2 * kp]);
                f16x2 w; w[0] = (_Float16)a.x; w[1] = (_Float16)a.y;
                W1loc[t][q] = __builtin_bit_cast(uint32_t, w);
            }
            const float2 bb = *reinterpret_cast<const float2*>(&b1[2 * kp]);
            f16x2 bh; bh[0] = (_Float16)bb.x; bh[1] = (_Float16)bb.y;
            b1loc[t] = __builtin_bit_cast(uint32_t, bh);
        }

        // g for this thread's row (broadcast f16 pairs as u32)
        const int m = mt * 128 + row;
        const float4 xv = *reinterpret_cast<const float4*>(x + (size_t)m * E_DIM);
        uint32_t gxu, gyu, gzu, gwu;
        {
            f16x2 v; _Float16 s;
            s = (_Float16)(cosf(xv.x) * cosf(theta[0])); v[0] = s; v[1] = s;
            gxu = __builtin_bit_cast(uint32_t, v);
            s = (_Float16)(cosf(xv.y) * cosf(theta[1])); v[0] = s; v[1] = s;
            gyu = __builtin_bit_cast(uint32_t, v);
            s = (_Float16)(cosf(xv.z) * cosf(theta[2])); v[0] = s; v[1] = s;
            gzu = __builtin_bit_cast(uint32_t, v);
            s = (_Float16)(cosf(xv.w) * cosf(theta[3])); v[0] = s; v[1] = s;
            gwu = __builtin_bit_cast(uint32_t, v);
        }
        const uint32_t zero_u = 0;
        __syncthreads();

        for (int kk = 0; kk < 8; ++kk) {
            const int kt = seg * 8 + kk;
            const int kpl = kk * 32 + half * 16;   // local kp base (16 pairs)
            uint32_t pm[16];
            #pragma unroll
            for (int pp = 0; pp < 16; ++pp) {
                const uint4 wq = *reinterpret_cast<const uint4*>(&W1loc[kpl + pp][0]);
                const uint32_t bp = b1loc[kpl + pp];
                uint32_t p_;
                asm("v_pk_fma_f16 %0, %1, %2, %3"
                    : "=v"(p_) : "v"(gxu), "v"(wq.x), "v"(bp));
                asm("v_pk_fma_f16 %0, %1, %2, %0"
                    : "+v"(p_) : "v"(gyu), "v"(wq.y));
                asm("v_pk_fma_f16 %0, %1, %2, %0"
                    : "+v"(p_) : "v"(gzu), "v"(wq.z));
                asm("v_pk_fma_f16 %0, %1, %2, %0"
                    : "+v"(p_) : "v"(gwu), "v"(wq.w));
                asm("v_pk_max_f16 %0, %0, %1"
                    : "+v"(p_) : "v"(zero_u));
                pm[pp] = p_;
            }
            // write 4 octets, slot-swizzled, into the half's 8KB image
            #pragma unroll
            for (int o = 0; o < 4; ++o) {
                const int slot = o ^ ((row >> 1) & 3);
                uint4 v;
                v.x = pm[4 * o]; v.y = pm[4 * o + 1];
                v.z = pm[4 * o + 2]; v.w = pm[4 * o + 3];
                *reinterpret_cast<uint4*>(&Hsm[half * 8192 + row * 64 + slot * 16]) = v;
            }
            __syncthreads();
            char* dst = ws + WS_A + ((size_t)mt * KT2 + 2 * kt) * ATILE;
            #pragma unroll
            for (int r = 0; r < 4; ++r) {
                const int c = r * 256 + t;
                *reinterpret_cast<uint4*>(dst + (size_t)c * 16) =
                    *reinterpret_cast<const uint4*>(&Hsm[c * 16]);
            }
            __syncthreads();
        }
    } else {
        // ---- W2 192-col tile (kt, nt) -> two 12KB swizzled f16 images ----
        __shared__ float Wf[64][196];
        const int idx = bid - MT * 6;                // 0..191
        const int kt  = idx >> 2;                    // 0..47
        const int nt  = idx & 3;                     // 0..3
        #pragma unroll
        for (int ii = 0; ii < 12; ++ii) {
            const int q = ii * 256 + t;              // 0..3071 float4s
            const int rw = q / 48;
            const int c4 = (q % 48) * 4;
            const float4 v = *reinterpret_cast<const float4*>(
                &W2[(size_t)(kt * 64 + rw) * E_DIM + nt * 192 + c4]);
            Wf[rw][c4] = v.x; Wf[rw][c4 + 1] = v.y;
            Wf[rw][c4 + 2] = v.z; Wf[rw][c4 + 3] = v.w;
        }
        __syncthreads();
        char* base = ws + WS_B + (size_t)(nt * KT2 + 2 * kt) * BTILE;
        #pragma unroll
        for (int cc = 0; cc < 6; ++cc) {
            const int c    = cc * 256 + t;           // 0..1535 chunks of 16B
            const int half = c / 768;
            const int q    = c - half * 768;
            const int rb   = q >> 2;                 // n-row 0..191
            const int slot = q & 3;
            const int oc   = slot ^ ((rb >> 1) & 3); // logical k-octet
            f16x8 v;
            #pragma unroll
            for (int j = 0; j < 8; ++j) v[j] = (_Float16)Wf[half * 32 + oc * 8 + j][rb];
            *reinterpret_cast<f16x8*>(base + (size_t)half * BTILE + (size_t)q * 16) = v;
        }
    }
}

// ---------------------------------------------------------------- GEMM ----
// Pure-load MFMA machine: no LDS, no barriers. 512thr / 8 waves (2M x 4N),
// block tile 128x192, wave tile 64x48. grid 512 = 2 blocks/CU.
__global__ __launch_bounds__(512, 4)
void ffq_gemm(const char* __restrict__ ws, const float* __restrict__ b2,
              float* __restrict__ out)
{
    const int t = threadIdx.x;
    const int lane = t & 63, wid = t >> 6;          // 8 waves

    // XCD mapping: each XCD owns 16 m-panels (128-row) x all 4 n-panels
    const int bid = blockIdx.x;                     // 512 = 8 * 64
    const int xcd = bid & 7;
    const int i   = bid >> 3;                       // 0..63
    const int mtb = xcd * 16 + (i & 15);            // 0..127
    const int nt  = i >> 4;                         // 0..3
    const int m0 = mtb * 128, n0 = nt * 192;

    const int wrm = wid & 1;                        // m-half (64 rows)
    const int wcn = wid >> 1;                       // n-quarter (48 cols)
    const int fr = lane & 15, fg = lane >> 4;

    const char* srcA = ws + WS_A + (size_t)mtb * KT2 * ATILE;
    const char* srcB = ws + WS_B + (size_t)nt * KT2 * BTILE;

    int offA[4], offB[3];
    #pragma unroll
    for (int mi = 0; mi < 4; ++mi) {
        const int rowp = wrm * 64 + mi * 16 + fr;
        const int sl = fg ^ ((rowp >> 1) & 3);
        offA[mi] = rowp * 64 + sl * 16;
    }
    #pragma unroll
    for (int ni = 0; ni < 3; ++ni) {
        const int rb = wcn * 48 + ni * 16 + fr;
        const int sl = fg ^ ((rb >> 1) & 3);
        offB[ni] = rb * 64 + sl * 16;
    }

    f32x4 acc[4][3] = {};
    f16x8 fa0[4], fa1[4], fb0[3], fb1[3];

    #define LOADA(kk, FA) do {                                                  \
        const char* sa_ = srcA + (size_t)(kk) * ATILE;                          \
        _Pragma("unroll")                                                       \
        for (int mi = 0; mi < 4; ++mi)                                          \
            FA[mi] = *reinterpret_cast<const f16x8*>(sa_ + offA[mi]);           \
        } while (0)

    #define LOADB(kk, FB) do {                                                  \
        const char* sb_ = srcB + (size_t)(kk) * BTILE;                          \
        _Pragma("unroll")                                                       \
        for (int ni = 0; ni < 3; ++ni)                                          \
            FB[ni] = *reinterpret_cast<const f16x8*>(sb_ + offB[ni]);           \
        } while (0)

    #define MFMA12(FA, FB) do {                                                 \
        _Pragma("unroll")                                                       \
        for (int mi = 0; mi < 4; ++mi)                                          \
            _Pragma("unroll")                                                   \
            for (int ni = 0; ni < 3; ++ni)                                      \
                acc[mi][ni] = __builtin_amdgcn_mfma_f32_16x16x32_f16(           \
                    FA[mi], FB[ni], acc[mi][ni], 0, 0, 0);                      \
        } while (0)

    // prologue: tiles 0,1 in flight (compiler orders via waitcnt deps)
    LOADA(0, fa0); LOADB(0, fb0);
    LOADA(1, fa1); LOADB(1, fb1);

    for (int p = 0; p < KT2 / 2 - 1; ++p) {          // k = 0..93
        MFMA12(fa0, fb0);
        LOADA(2 * p + 2, fa0); LOADB(2 * p + 2, fb0);
        MFMA12(fa1, fb1);
        LOADA(2 * p + 3, fa1); LOADB(2 * p + 3, fb1);
    }
    MFMA12(fa0, fb0);                                // k = 94
    MFMA12(fa1, fb1);                                // k = 95

    #undef LOADA
    #undef LOADB
    #undef MFMA12

    // epilogue (C/D: col=lane&15, row=(lane>>4)*4+r)
    #pragma unroll
    for (int ni = 0; ni < 3; ++ni) {
        const int col = n0 + wcn * 48 + ni * 16 + fr;
        const float bias = b2[col];
        #pragma unroll
        for (int mi = 0; mi < 4; ++mi) {
            #pragma unroll
            for (int rr = 0; rr < 4; ++rr) {
                const int ro = m0 + wrm * 64 + mi * 16 + fg * 4 + rr;
                out[(size_t)ro * E_DIM + col] = acc[mi][ni][rr] + bias;
            }
        }
    }
}

// ------------------------------------------- fallback: round-1 fused ------
__global__ __launch_bounds__(256, 2)
void ffq_fused(const float* __restrict__ x, const float* __restrict__ theta,
               const float* __restrict__ W1, const float* __restrict__ b1,
               const float* __restrict__ W2, const float* __restrict__ b2,
               float* __restrict__ out)
{
    __shared__ bf16_t Asm[BM][BK];
    __shared__ bf16_t Bsm[BN][BK];
    __shared__ float  gsm[BM][4];
    __shared__ float  b2sm[BN];

    const int t = threadIdx.x;
    const int lane = t & 63, wid = t >> 6;
    const int bid = blockIdx.x;
    const int swz = (bid & 7) * (MT * NT / 8) + (bid >> 3);
    const int ntile = swz / MT, mtile = swz % MT;
    const int m0 = mtile * BM, n0 = ntile * BN;

    const float c0 = cosf(theta[0]), c1 = cosf(theta[1]);
    const float c2 = cosf(theta[2]), c3 = cosf(theta[3]);
    if (t < BM) {
        const float4 xv = *reinterpret_cast<const float4*>(x + (size_t)(m0 + t) * E_DIM);
        gsm[t][0] = cosf(xv.x) * c0; gsm[t][1] = cosf(xv.y) * c1;
        gsm[t][2] = cosf(xv.z) * c2; gsm[t][3] = cosf(xv.w) * c3;
    } else {
        const int n = t - 128;
        b2sm[n] = b2[n0 + n];
    }
    __syncthreads();

    const int rg = t >> 3, kg = t & 7;
    const int nB = t & 127, kh = t >> 7;
    const int wr = wid >> 1, wc = wid & 1;
    const int fr = lane & 15, fg = lane >> 4;

    f32x4 acc[4][4] = {};

    for (int k0 = 0; k0 < F_DIM; k0 += BK) {
        {
            const int kA = k0 + (kg << 3);
            float w1v[4][8], b1v[8];
            #pragma unroll
            for (int q = 0; q < 4; ++q) {
                const float4 lo = *reinterpret_cast<const float4*>(&W1[q * F_DIM + kA]);
                const float4 hi = *reinterpret_cast<const float4*>(&W1[q * F_DIM + kA + 4]);
                w1v[q][0] = lo.x; w1v[q][1] = lo.y; w1v[q][2] = lo.z; w1v[q][3] = lo.w;
                w1v[q][4] = hi.x; w1v[q][5] = hi.y; w1v[q][6] = hi.z; w1v[q][7] = hi.w;
            }
            {
                const float4 lo = *reinterpret_cast<const float4*>(&b1[kA]);
                const float4 hi = *reinterpret_cast<const float4*>(&b1[kA + 4]);
                b1v[0] = lo.x; b1v[1] = lo.y; b1v[2] = lo.z; b1v[3] = lo.w;
                b1v[4] = hi.x; b1v[5] = hi.y; b1v[6] = hi.z; b1v[7] = hi.w;
            }
            #pragma unroll
            for (int r = 0; r < 4; ++r) {
                const int row = (rg << 2) + r;
                const float4 g = *reinterpret_cast<const float4*>(&gsm[row][0]);
                bf16x8 v;
                #pragma unroll
                for (int kk = 0; kk < 8; ++kk) {
                    float p = b1v[kk];
                    p = fmaf(g.x, w1v[0][kk], p);
                    p = fmaf(g.y, w1v[1][kk], p);
                    p = fmaf(g.z, w1v[2][kk], p);
                    p = fmaf(g.w, w1v[3][kk], p);
                    v[kk] = (bf16_t)fmaxf(p, 0.0f);
                }
                *reinterpret_cast<bf16x8*>(&Asm[row][(kg ^ (row & 7)) << 3]) = v;
            }
        }
        {
            const float* w2p = W2 + (size_t)(k0 + (kh << 5)) * E_DIM + n0 + nB;
            float bv[32];
            #pragma unroll
            for (int kk = 0; kk < 32; ++kk) bv[kk] = w2p[kk * E_DIM];
            #pragma unroll
            for (int o = 0; o < 4; ++o) {
                bf16x8 v;
                #pragma unroll
                for (int j = 0; j < 8; ++j) v[j] = (bf16_t)bv[(o << 3) + j];
                *reinterpret_cast<bf16x8*>(&Bsm[nB][(((kh << 2) + o) ^ (nB & 7)) << 3]) = v;
            }
        }
        __syncthreads();
        #pragma unroll
        for (int ks = 0; ks < 2; ++ks) {
            const int kob = (ks << 2) + fg;
            bf16x8 af[4], bfr[4];
            #pragma unroll
            for (int mi = 0; mi < 4; ++mi) {
                const int row = (wr << 6) + (mi << 4) + fr;
                af[mi] = *reinterpret_cast<const bf16x8*>(&Asm[row][(kob ^ (row & 7)) << 3]);
            }
            #pragma unroll
            for (int ni = 0; ni < 4; ++ni) {
                const int rn = (wc << 6) + (ni << 4) + fr;
                bfr[ni] = *reinterpret_cast<const bf16x8*>(&Bsm[rn][(kob ^ (rn & 7)) << 3]);
            }
            #pragma unroll
            for (int mi = 0; mi < 4; ++mi)
                #pragma unroll
                for (int ni = 0; ni < 4; ++ni)
                    acc[mi][ni] = __builtin_amdgcn_mfma_f32_16x16x32_bf16(
                        af[mi], bfr[ni], acc[mi][ni], 0, 0, 0);
        }
        __syncthreads();
    }

    #pragma unroll
    for (int mi = 0; mi < 4; ++mi)
        #pragma unroll
        for (int ni = 0; ni < 4; ++ni) {
            const int col  = n0 + (wc << 6) + (ni << 4) + fr;
            const float bias = b2sm[(wc << 6) + (ni << 4) + fr];
            #pragma unroll
            for (int r = 0; r < 4; ++r) {
                const int row = m0 + (wr << 6) + (mi << 4) + (fg << 2) + r;
                out[(size_t)row * E_DIM + col] = acc[mi][ni][r] + bias;
            }
        }
}

// -------------------------------------------------------------- launch ----
extern "C" void kernel_launch(void* const* d_in, const int* in_sizes, int n_in,
                              void* d_out, int out_size, void* d_ws, size_t ws_size,
                              hipStream_t stream) {
    const float* x     = (const float*)d_in[0];
    const float* theta = (const float*)d_in[1];
    const float* W1    = (const float*)d_in[2];
    const float* b1    = (const float*)d_in[3];
    const float* W2    = (const float*)d_in[4];
    const float* b2    = (const float*)d_in[5];
    float* out = (float*)d_out;

    if (ws_size >= WS_NEED) {
        hipLaunchKernelGGL(ffq_prep, dim3(MT * 6 + 192), dim3(256), 0, stream,
                           x, theta, W1, b1, W2, (char*)d_ws);
        hipLaunchKernelGGL(ffq_gemm, dim3(512), dim3(512), 0, stream,
                           (const char*)d_ws, b2, out);
    } else {
        hipLaunchKernelGGL(ffq_fused, dim3(MT * NT), dim3(256), 0, stream,
                           x, theta, W1, b1, W2, b2, out);
    }
}

// Round 19
// 104.048 us; speedup vs baseline: 1.2952x; 1.2952x over previous
//
#include <hip/hip_runtime.h>
#include <hip/hip_bf16.h>
#include <math.h>
#include <stdint.h>

// Round 19: r16 + ring-3 register buffers (breaks the LOADB WAR hazard so
// B-loads issue a full k-step early) + s_setprio around the MFMA cluster.
// Everything else identical to r16: barrier-free K-loop, packed-f16 AGEN
// from LDS W1^T, B frags direct global->VGPR from prebaked swizzled images,
// mfma_f32_16x16x32_f16, 256x192 block / 8 waves (4M x 2N) / grid 256.

typedef __bf16 bf16_t;
typedef __attribute__((ext_vector_type(8))) __bf16 bf16x8;
typedef __attribute__((ext_vector_type(8))) _Float16 f16x8;
typedef __attribute__((ext_vector_type(2))) _Float16 f16x2;
typedef __attribute__((ext_vector_type(4))) float f32x4;

#define M_TOT 16384
#define E_DIM 768
#define F_DIM 3072

constexpr int BM = 128, BN = 128, BK = 64;   // legacy (fallback only)
constexpr int MT = M_TOT / BM;    // fallback
constexpr int NT = E_DIM / BN;    // fallback
constexpr int KT = F_DIM / BK;    // 48
constexpr int KT2 = 2 * KT;       // 96 k-steps (K=32)
constexpr int BTILE = 12288;      // 192x32 f16 B tile image bytes
constexpr int NT4 = 4;            // 192-col B panels

// ws layout
constexpr size_t WS_B2   = 0;                                    // 4*96*12288
constexpr size_t WS_G    = WS_B2 + (size_t)NT4 * KT2 * BTILE;    // 16384 float4
constexpr size_t WS_NEED = WS_G + (size_t)M_TOT * 16;            // ~5 MiB

// ---------------------------------------------------- prep (g + W2) ----
__global__ __launch_bounds__(256)
void ffq_prep(const float* __restrict__ x, const float* __restrict__ theta,
              const float* __restrict__ W2, char* __restrict__ ws)
{
    const int t = threadIdx.x;
    const int bid = blockIdx.x;

    if (bid < 64) {
        // ---- g[m] = cos(x[m,0:4]) * cos(theta) ----
        const int m = bid * 256 + t;
        const float4 xv = *reinterpret_cast<const float4*>(x + (size_t)m * E_DIM);
        float4 g;
        g.x = cosf(xv.x) * cosf(theta[0]);
        g.y = cosf(xv.y) * cosf(theta[1]);
        g.z = cosf(xv.z) * cosf(theta[2]);
        g.w = cosf(xv.w) * cosf(theta[3]);
        *reinterpret_cast<float4*>(ws + WS_G + (size_t)m * 16) = g;
    } else {
        // ---- W2 192-col tile (kt, nt) -> two 12KB swizzled f16 k-half images ----
        __shared__ float Wf[64][196];
        const int idx = bid - 64;                    // 0..191
        const int kt  = idx >> 2;                    // 0..47
        const int nt  = idx & 3;                     // 0..3
        #pragma unroll
        for (int ii = 0; ii < 12; ++ii) {
            const int q = ii * 256 + t;              // 0..3071 float4s
            const int row = q / 48;
            const int c4  = (q % 48) * 4;
            const float4 v = *reinterpret_cast<const float4*>(
                &W2[(size_t)(kt * 64 + row) * E_DIM + nt * 192 + c4]);
            Wf[row][c4] = v.x; Wf[row][c4 + 1] = v.y;
            Wf[row][c4 + 2] = v.z; Wf[row][c4 + 3] = v.w;
        }
        __syncthreads();
        char* base = ws + WS_B2 + (size_t)(nt * KT2 + 2 * kt) * BTILE;
        #pragma unroll
        for (int cc = 0; cc < 6; ++cc) {
            const int c    = cc * 256 + t;           // 0..1535 chunks of 16B
            const int half = c / 768;
            const int q    = c - half * 768;
            const int rb   = q >> 2;                 // n-row 0..191
            const int slot = q & 3;
            const int oc   = slot ^ ((rb >> 1) & 3); // logical k-octet
            f16x8 v;
            #pragma unroll
            for (int j = 0; j < 8; ++j) v[j] = (_Float16)Wf[half * 32 + oc * 8 + j][rb];
            *reinterpret_cast<f16x8*>(base + (size_t)half * BTILE + (size_t)q * 16) = v;
        }
    }
}

// ---------------------------------------------------------------- GEMM ----
__global__ __launch_bounds__(512, 1)
void ffq_gemm(const char* __restrict__ ws, const float* __restrict__ W1,
              const float* __restrict__ b1, const float* __restrict__ b2,
              float* __restrict__ out)
{
    __shared__ __align__(16) f16x2 W1i[F_DIM / 2][4];  // 24KB: [kp][q] pairs
    __shared__ f16x2 b1h[F_DIM / 2];                   // 6KB

    const int t = threadIdx.x;
    const int lane = t & 63, wid = t >> 6;          // 8 waves

    // XCD mapping: each XCD owns 8 m-panels (256-row) x all 4 n-panels
    const int bid = blockIdx.x;                     // 256 = 8 * 32
    const int xcd = bid & 7;
    const int i   = bid >> 3;                       // 0..31
    const int mtb = xcd * 8 + (i & 7);              // 0..63
    const int nt  = i >> 3;                         // 0..3
    const int m0 = mtb * 256, n0 = nt * 192;

    const int wrm = wid & 3;                        // m-quadrant (64 rows)
    const int wcn = wid >> 2;                       // n-half (96 cols)
    const int fr = lane & 15, fg = lane >> 4;

    const char* srcB = ws + WS_B2 + (size_t)nt * KT2 * BTILE;
    const float4* garr = reinterpret_cast<const float4*>(ws + WS_G);

    // read-only LDS panels: W1 k-pair quads + b1 pairs (f16)
    #pragma unroll
    for (int ii = 0; ii < 3; ++ii) {
        const int kp = ii * 512 + t;
        #pragma unroll
        for (int q = 0; q < 4; ++q) {
            const float2 a = *reinterpret_cast<const float2*>(&W1[(size_t)q * F_DIM + 2 * kp]);
            f16x2 w; w[0] = (_Float16)a.x; w[1] = (_Float16)a.y;
            W1i[kp][q] = w;
        }
        const float2 bb = *reinterpret_cast<const float2*>(&b1[2 * kp]);
        f16x2 bh; bh[0] = (_Float16)bb.x; bh[1] = (_Float16)bb.y;
        b1h[kp] = bh;
    }

    float4 g4[4];
    #pragma unroll
    for (int mi = 0; mi < 4; ++mi)
        g4[mi] = garr[m0 + wrm * 64 + mi * 16 + fr];

    // broadcast g as packed f16 pairs, kept as u32 for VOP3P asm
    uint32_t gxu[4], gyu[4], gzu[4], gwu[4];
    #pragma unroll
    for (int mi = 0; mi < 4; ++mi) {
        f16x2 v;
        v[0] = (_Float16)g4[mi].x; v[1] = (_Float16)g4[mi].x;
        gxu[mi] = __builtin_bit_cast(uint32_t, v);
        v[0] = (_Float16)g4[mi].y; v[1] = (_Float16)g4[mi].y;
        gyu[mi] = __builtin_bit_cast(uint32_t, v);
        v[0] = (_Float16)g4[mi].z; v[1] = (_Float16)g4[mi].z;
        gzu[mi] = __builtin_bit_cast(uint32_t, v);
        v[0] = (_Float16)g4[mi].w; v[1] = (_Float16)g4[mi].w;
        gwu[mi] = __builtin_bit_cast(uint32_t, v);
    }
    const uint32_t zero_u = 0;

    __syncthreads();   // the only barrier in this kernel

    // per-thread B fragment byte offsets within one tile image
    int offB[6];
    #pragma unroll
    for (int ni = 0; ni < 6; ++ni) {
        const int rb = wcn * 96 + ni * 16 + fr;
        const int sl = fg ^ ((rb >> 1) & 3);
        offB[ni] = rb * 64 + sl * 16;
    }

    f32x4 acc[4][6] = {};
    f16x8 fa0[4], fa1[4], fa2[4], fb0[6], fb1[6], fb2[6];

    // A-frag gen: v_pk_fma_f16 / v_pk_max_f16 (r16-proven)
    #define AGEN(kk, FA) do {                                                   \
        const int kp0_ = (kk) * 16 + fg * 4;                                    \
        uint32_t pm_[4][4];                                                     \
        _Pragma("unroll")                                                       \
        for (int c_ = 0; c_ < 4; ++c_) {                                        \
            const uint4 wr_ = *reinterpret_cast<const uint4*>(&W1i[kp0_ + c_][0]); \
            const uint32_t bp_ = __builtin_bit_cast(uint32_t, b1h[kp0_ + c_]);  \
            _Pragma("unroll")                                                   \
            for (int mi = 0; mi < 4; ++mi) {                                    \
                uint32_t p_;                                                    \
                asm("v_pk_fma_f16 %0, %1, %2, %3"                               \
                    : "=v"(p_) : "v"(gxu[mi]), "v"(wr_.x), "v"(bp_));           \
                asm("v_pk_fma_f16 %0, %1, %2, %0"                               \
                    : "+v"(p_) : "v"(gyu[mi]), "v"(wr_.y));                     \
                asm("v_pk_fma_f16 %0, %1, %2, %0"                               \
                    : "+v"(p_) : "v"(gzu[mi]), "v"(wr_.z));                     \
                asm("v_pk_fma_f16 %0, %1, %2, %0"                               \
                    : "+v"(p_) : "v"(gwu[mi]), "v"(wr_.w));                     \
                asm("v_pk_max_f16 %0, %0, %1"                                   \
                    : "+v"(p_) : "v"(zero_u));                                  \
                pm_[mi][c_] = p_;                                               \
            }                                                                   \
        }                                                                       \
        _Pragma("unroll")                                                       \
        for (int mi = 0; mi < 4; ++mi) {                                        \
            uint4 t_;                                                           \
            t_.x = pm_[mi][0]; t_.y = pm_[mi][1];                               \
            t_.z = pm_[mi][2]; t_.w = pm_[mi][3];                               \
            FA[mi] = __builtin_bit_cast(f16x8, t_);                             \
        } } while (0)

    // 6 global_load_dwordx4: B frags straight to VGPR (L1/L2-hit)
    #define LOADB(kk, FB) do {                                                  \
        const char* sb_ = srcB + (size_t)(kk) * BTILE;                          \
        _Pragma("unroll")                                                       \
        for (int ni = 0; ni < 6; ++ni)                                          \
            FB[ni] = *reinterpret_cast<const f16x8*>(sb_ + offB[ni]);           \
        } while (0)

    #define MFMA24(FA, FB) do {                                                 \
        __builtin_amdgcn_s_setprio(1);                                          \
        _Pragma("unroll")                                                       \
        for (int mi = 0; mi < 4; ++mi)                                          \
            _Pragma("unroll")                                                   \
            for (int ni = 0; ni < 6; ++ni)                                      \
                acc[mi][ni] = __builtin_amdgcn_mfma_f32_16x16x32_f16(           \
                    FA[mi], FB[ni], acc[mi][ni], 0, 0, 0);                      \
        __builtin_amdgcn_s_setprio(0);                                          \
    } while (0)

    // prologue: tiles 0,1 into regs
    LOADB(0, fb0); AGEN(0, fa0);
    LOADB(1, fb1); AGEN(1, fa1);

    // ring-3 steady state: LOADB(k+2) issues BEFORE MFMA(k) (no WAR hazard)
    for (int p = 0; p < 31; ++p) {                   // k = 0..92
        LOADB(3 * p + 2, fb2); AGEN(3 * p + 2, fa2); MFMA24(fa0, fb0);
        LOADB(3 * p + 3, fb0); AGEN(3 * p + 3, fa0); MFMA24(fa1, fb1);
        LOADB(3 * p + 4, fb1); AGEN(3 * p + 4, fa1); MFMA24(fa2, fb2);
    }
    // k = 93 (issues tile 95), 94, 95
    LOADB(95, fb2); AGEN(95, fa2); MFMA24(fa0, fb0);
    MFMA24(fa1, fb1);
    MFMA24(fa2, fb2);

    #undef AGEN
    #undef LOADB
    #undef MFMA24

    // epilogue (C/D: col=lane&15, row=(lane>>4)*4+r)
    #pragma unroll
    for (int ni = 0; ni < 6; ++ni) {
        const int col = n0 + wcn * 96 + ni * 16 + fr;
        const float bias = b2[col];
        #pragma unroll
        for (int mi = 0; mi < 4; ++mi) {
            #pragma unroll
            for (int rr = 0; rr < 4; ++rr) {
                const int ro = m0 + wrm * 64 + mi * 16 + fg * 4 + rr;
                out[(size_t)ro * E_DIM + col] = acc[mi][ni][rr] + bias;
            }
        }
    }
}

// ------------------------------------------- fallback: round-1 fused ------
__global__ __launch_bounds__(256, 2)
void ffq_fused(const float* __restrict__ x, const float* __restrict__ theta,
               const float* __restrict__ W1, const float* __restrict__ b1,
               const float* __restrict__ W2, const float* __restrict__ b2,
               float* __restrict__ out)
{
    __shared__ bf16_t Asm[BM][BK];
    __shared__ bf16_t Bsm[BN][BK];
    __shared__ float  gsm[BM][4];
    __shared__ float  b2sm[BN];

    const int t = threadIdx.x;
    const int lane = t & 63, wid = t >> 6;
    const int bid = blockIdx.x;
    const int swz = (bid & 7) * (MT * NT / 8) + (bid >> 3);
    const int ntile = swz / MT, mtile = swz % MT;
    const int m0 = mtile * BM, n0 = ntile * BN;

    const float c0 = cosf(theta[0]), c1 = cosf(theta[1]);
    const float c2 = cosf(theta[2]), c3 = cosf(theta[3]);
    if (t < BM) {
        const float4 xv = *reinterpret_cast<const float4*>(x + (size_t)(m0 + t) * E_DIM);
        gsm[t][0] = cosf(xv.x) * c0; gsm[t][1] = cosf(xv.y) * c1;
        gsm[t][2] = cosf(xv.z) * c2; gsm[t][3] = cosf(xv.w) * c3;
    } else {
        const int n = t - 128;
        b2sm[n] = b2[n0 + n];
    }
    __syncthreads();

    const int rg = t >> 3, kg = t & 7;
    const int nB = t & 127, kh = t >> 7;
    const int wr = wid >> 1, wc = wid & 1;
    const int fr = lane & 15, fg = lane >> 4;

    f32x4 acc[4][4] = {};

    for (int k0 = 0; k0 < F_DIM; k0 += BK) {
        {
            const int kA = k0 + (kg << 3);
            float w1v[4][8], b1v[8];
            #pragma unroll
            for (int q = 0; q < 4; ++q) {
                const float4 lo = *reinterpret_cast<const float4*>(&W1[q * F_DIM + kA]);
                const float4 hi = *reinterpret_cast<const float4*>(&W1[q * F_DIM + kA + 4]);
                w1v[q][0] = lo.x; w1v[q][1] = lo.y; w1v[q][2] = lo.z; w1v[q][3] = lo.w;
                w1v[q][4] = hi.x; w1v[q][5] = hi.y; w1v[q][6] = hi.z; w1v[q][7] = hi.w;
            }
            {
                const float4 lo = *reinterpret_cast<const float4*>(&b1[kA]);
                const float4 hi = *reinterpret_cast<const float4*>(&b1[kA + 4]);
                b1v[0] = lo.x; b1v[1] = lo.y; b1v[2] = lo.z; b1v[3] = lo.w;
                b1v[4] = hi.x; b1v[5] = hi.y; b1v[6] = hi.z; b1v[7] = hi.w;
            }
            #pragma unroll
            for (int r = 0; r < 4; ++r) {
                const int row = (rg << 2) + r;
                const float4 g = *reinterpret_cast<const float4*>(&gsm[row][0]);
                bf16x8 v;
                #pragma unroll
                for (int kk = 0; kk < 8; ++kk) {
                    float p = b1v[kk];
                    p = fmaf(g.x, w1v[0][kk], p);
                    p = fmaf(g.y, w1v[1][kk], p);
                    p = fmaf(g.z, w1v[2][kk], p);
                    p = fmaf(g.w, w1v[3][kk], p);
                    v[kk] = (bf16_t)fmaxf(p, 0.0f);
                }
                *reinterpret_cast<bf16x8*>(&Asm[row][(kg ^ (row & 7)) << 3]) = v;
            }
        }
        {
            const float* w2p = W2 + (size_t)(k0 + (kh << 5)) * E_DIM + n0 + nB;
            float bv[32];
            #pragma unroll
            for (int kk = 0; kk < 32; ++kk) bv[kk] = w2p[kk * E_DIM];
            #pragma unroll
            for (int o = 0; o < 4; ++o) {
                bf16x8 v;
                #pragma unroll
                for (int j = 0; j < 8; ++j) v[j] = (bf16_t)bv[(o << 3) + j];
                *reinterpret_cast<bf16x8*>(&Bsm[nB][(((kh << 2) + o) ^ (nB & 7)) << 3]) = v;
            }
        }
        __syncthreads();
        #pragma unroll
        for (int ks = 0; ks < 2; ++ks) {
            const int kob = (ks << 2) + fg;
            bf16x8 af[4], bfr[4];
            #pragma unroll
            for (int mi = 0; mi < 4; ++mi) {
                const int row = (wr << 6) + (mi << 4) + fr;
                af[mi] = *reinterpret_cast<const bf16x8*>(&Asm[row][(kob ^ (row & 7)) << 3]);
            }
            #pragma unroll
            for (int ni = 0; ni < 4; ++ni) {
                const int rn = (wc << 6) + (ni << 4) + fr;
                bfr[ni] = *reinterpret_cast<const bf16x8*>(&Bsm[rn][(kob ^ (rn & 7)) << 3]);
            }
            #pragma unroll
            for (int mi = 0; mi < 4; ++mi)
                #pragma unroll
                for (int ni = 0; ni < 4; ++ni)
                    acc[mi][ni] = __builtin_amdgcn_mfma_f32_16x16x32_bf16(
                        af[mi], bfr[ni], acc[mi][ni], 0, 0, 0);
        }
        __syncthreads();
    }

    #pragma unroll
    for (int mi = 0; mi < 4; ++mi)
        #pragma unroll
        for (int ni = 0; ni < 4; ++ni) {
            const int col  = n0 + (wc << 6) + (ni << 4) + fr;
            const float bias = b2sm[(wc << 6) + (ni << 4) + fr];
            #pragma unroll
            for (int r = 0; r < 4; ++r) {
                const int row = m0 + (wr << 6) + (mi << 4) + (fg << 2) + r;
                out[(size_t)row * E_DIM + col] = acc[mi][ni][r] + bias;
            }
        }
}

// -------------------------------------------------------------- launch ----
extern "C" void kernel_launch(void* const* d_in, const int* in_sizes, int n_in,
                              void* d_out, int out_size, void* d_ws, size_t ws_size,
                              hipStream_t stream) {
    const float* x     = (const float*)d_in[0];
    const float* theta = (const float*)d_in[1];
    const float* W1    = (const float*)d_in[2];
    const float* b1    = (const float*)d_in[3];
    const float* W2    = (const float*)d_in[4];
    const float* b2    = (const float*)d_in[5];
    float* out = (float*)d_out;

    if (ws_size >= WS_NEED) {
        hipLaunchKernelGGL(ffq_prep, dim3(256), dim3(256), 0, stream,
                           x, theta, W2, (char*)d_ws);
        hipLaunchKernelGGL(ffq_gemm, dim3(256), dim3(512), 0, stream,
                           (const char*)d_ws, W1, b1, b2, out);
    } else {
        hipLaunchKernelGGL(ffq_fused, dim3(MT * NT), dim3(256), 0, stream,
                           x, theta, W1, b1, W2, b2, out);
    }
}

// Round 20
// 83.960 us; speedup vs baseline: 1.6051x; 1.2393x over previous
//
#include <hip/hip_runtime.h>
#include <hip/hip_bf16.h>
#include <math.h>
#include <stdint.h>

// Round 20: RESTORE round 16 (best measured: 84.0 us total) byte-identical.
// Barrier-free fused GEMM: packed-f16 AGEN (v_pk_fma_f16/v_pk_max_f16 asm)
// from read-only LDS W1^T/b1 panels; B frags direct global->VGPR from
// prebaked swizzled f16 images; mfma_f32_16x16x32_f16; 256x192 block,
// 8 waves (4M x 2N), grid 256; 2-deep register double-buffer.
// r17 (more waves), r18 (h-materialize), r19 (ring-3) all regressed —
// this is the combined-issue-bound plateau of the fused-AGEN design.

typedef __bf16 bf16_t;
typedef __attribute__((ext_vector_type(8))) __bf16 bf16x8;
typedef __attribute__((ext_vector_type(8))) _Float16 f16x8;
typedef __attribute__((ext_vector_type(2))) _Float16 f16x2;
typedef __attribute__((ext_vector_type(4))) float f32x4;

#define M_TOT 16384
#define E_DIM 768
#define F_DIM 3072

constexpr int BM = 128, BN = 128, BK = 64;   // legacy (fallback only)
constexpr int MT = M_TOT / BM;    // fallback
constexpr int NT = E_DIM / BN;    // fallback
constexpr int KT = F_DIM / BK;    // 48
constexpr int KT2 = 2 * KT;       // 96 k-steps (K=32)
constexpr int BTILE = 12288;      // 192x32 f16 B tile image bytes
constexpr int NT4 = 4;            // 192-col B panels

// ws layout
constexpr size_t WS_B2   = 0;                                    // 4*96*12288
constexpr size_t WS_G    = WS_B2 + (size_t)NT4 * KT2 * BTILE;    // 16384 float4
constexpr size_t WS_NEED = WS_G + (size_t)M_TOT * 16;            // ~5 MiB

// ---------------------------------------------------- prep (g + W2) ----
__global__ __launch_bounds__(256)
void ffq_prep(const float* __restrict__ x, const float* __restrict__ theta,
              const float* __restrict__ W2, char* __restrict__ ws)
{
    const int t = threadIdx.x;
    const int bid = blockIdx.x;

    if (bid < 64) {
        // ---- g[m] = cos(x[m,0:4]) * cos(theta) ----
        const int m = bid * 256 + t;
        const float4 xv = *reinterpret_cast<const float4*>(x + (size_t)m * E_DIM);
        float4 g;
        g.x = cosf(xv.x) * cosf(theta[0]);
        g.y = cosf(xv.y) * cosf(theta[1]);
        g.z = cosf(xv.z) * cosf(theta[2]);
        g.w = cosf(xv.w) * cosf(theta[3]);
        *reinterpret_cast<float4*>(ws + WS_G + (size_t)m * 16) = g;
    } else {
        // ---- W2 192-col tile (kt, nt) -> two 12KB swizzled f16 k-half images ----
        __shared__ float Wf[64][196];
        const int idx = bid - 64;                    // 0..191
        const int kt  = idx >> 2;                    // 0..47
        const int nt  = idx & 3;                     // 0..3
        #pragma unroll
        for (int ii = 0; ii < 12; ++ii) {
            const int q = ii * 256 + t;              // 0..3071 float4s
            const int row = q / 48;
            const int c4  = (q % 48) * 4;
            const float4 v = *reinterpret_cast<const float4*>(
                &W2[(size_t)(kt * 64 + row) * E_DIM + nt * 192 + c4]);
            Wf[row][c4] = v.x; Wf[row][c4 + 1] = v.y;
            Wf[row][c4 + 2] = v.z; Wf[row][c4 + 3] = v.w;
        }
        __syncthreads();
        char* base = ws + WS_B2 + (size_t)(nt * KT2 + 2 * kt) * BTILE;
        #pragma unroll
        for (int cc = 0; cc < 6; ++cc) {
            const int c    = cc * 256 + t;           // 0..1535 chunks of 16B
            const int half = c / 768;
            const int q    = c - half * 768;
            const int rb   = q >> 2;                 // n-row 0..191
            const int slot = q & 3;
            const int oc   = slot ^ ((rb >> 1) & 3); // logical k-octet
            f16x8 v;
            #pragma unroll
            for (int j = 0; j < 8; ++j) v[j] = (_Float16)Wf[half * 32 + oc * 8 + j][rb];
            *reinterpret_cast<f16x8*>(base + (size_t)half * BTILE + (size_t)q * 16) = v;
        }
    }
}

// ---------------------------------------------------------------- GEMM ----
__global__ __launch_bounds__(512, 1)
void ffq_gemm(const char* __restrict__ ws, const float* __restrict__ W1,
              const float* __restrict__ b1, const float* __restrict__ b2,
              float* __restrict__ out)
{
    __shared__ __align__(16) f16x2 W1i[F_DIM / 2][4];  // 24KB: [kp][q] pairs
    __shared__ f16x2 b1h[F_DIM / 2];                   // 6KB

    const int t = threadIdx.x;
    const int lane = t & 63, wid = t >> 6;          // 8 waves

    // XCD mapping: each XCD owns 8 m-panels (256-row) x all 4 n-panels
    const int bid = blockIdx.x;                     // 256 = 8 * 32
    const int xcd = bid & 7;
    const int i   = bid >> 3;                       // 0..31
    const int mtb = xcd * 8 + (i & 7);              // 0..63
    const int nt  = i >> 3;                         // 0..3
    const int m0 = mtb * 256, n0 = nt * 192;

    const int wrm = wid & 3;                        // m-quadrant (64 rows)
    const int wcn = wid >> 2;                       // n-half (96 cols)
    const int fr = lane & 15, fg = lane >> 4;

    const char* srcB = ws + WS_B2 + (size_t)nt * KT2 * BTILE;
    const float4* garr = reinterpret_cast<const float4*>(ws + WS_G);

    // read-only LDS panels: W1 k-pair quads + b1 pairs (f16)
    #pragma unroll
    for (int ii = 0; ii < 3; ++ii) {
        const int kp = ii * 512 + t;
        #pragma unroll
        for (int q = 0; q < 4; ++q) {
            const float2 a = *reinterpret_cast<const float2*>(&W1[(size_t)q * F_DIM + 2 * kp]);
            f16x2 w; w[0] = (_Float16)a.x; w[1] = (_Float16)a.y;
            W1i[kp][q] = w;
        }
        const float2 bb = *reinterpret_cast<const float2*>(&b1[2 * kp]);
        f16x2 bh; bh[0] = (_Float16)bb.x; bh[1] = (_Float16)bb.y;
        b1h[kp] = bh;
    }

    float4 g4[4];
    #pragma unroll
    for (int mi = 0; mi < 4; ++mi)
        g4[mi] = garr[m0 + wrm * 64 + mi * 16 + fr];

    // broadcast g as packed f16 pairs, kept as u32 for VOP3P asm
    uint32_t gxu[4], gyu[4], gzu[4], gwu[4];
    #pragma unroll
    for (int mi = 0; mi < 4; ++mi) {
        f16x2 v;
        v[0] = (_Float16)g4[mi].x; v[1] = (_Float16)g4[mi].x;
        gxu[mi] = __builtin_bit_cast(uint32_t, v);
        v[0] = (_Float16)g4[mi].y; v[1] = (_Float16)g4[mi].y;
        gyu[mi] = __builtin_bit_cast(uint32_t, v);
        v[0] = (_Float16)g4[mi].z; v[1] = (_Float16)g4[mi].z;
        gzu[mi] = __builtin_bit_cast(uint32_t, v);
        v[0] = (_Float16)g4[mi].w; v[1] = (_Float16)g4[mi].w;
        gwu[mi] = __builtin_bit_cast(uint32_t, v);
    }
    const uint32_t zero_u = 0;

    __syncthreads();   // the only barrier in this kernel

    // per-thread B fragment byte offsets within one tile image
    int offB[6];
    #pragma unroll
    for (int ni = 0; ni < 6; ++ni) {
        const int rb = wcn * 96 + ni * 16 + fr;
        const int sl = fg ^ ((rb >> 1) & 3);
        offB[ni] = rb * 64 + sl * 16;
    }

    f32x4 acc[4][6] = {};
    f16x8 fa0[4], fa1[4], fb0[6], fb1[6];

    // A-frag gen: forced v_pk_fma_f16 / v_pk_max_f16 (VOP3P), u32 lanes
    #define AGEN(kk, FA) do {                                                   \
        const int kp0_ = (kk) * 16 + fg * 4;                                    \
        uint32_t pm_[4][4];                                                     \
        _Pragma("unroll")                                                       \
        for (int c_ = 0; c_ < 4; ++c_) {                                        \
            const uint4 wr_ = *reinterpret_cast<const uint4*>(&W1i[kp0_ + c_][0]); \
            const uint32_t bp_ = __builtin_bit_cast(uint32_t, b1h[kp0_ + c_]);  \
            _Pragma("unroll")                                                   \
            for (int mi = 0; mi < 4; ++mi) {                                    \
                uint32_t p_;                                                    \
                asm("v_pk_fma_f16 %0, %1, %2, %3"                               \
                    : "=v"(p_) : "v"(gxu[mi]), "v"(wr_.x), "v"(bp_));           \
                asm("v_pk_fma_f16 %0, %1, %2, %0"                               \
                    : "+v"(p_) : "v"(gyu[mi]), "v"(wr_.y));                     \
                asm("v_pk_fma_f16 %0, %1, %2, %0"                               \
                    : "+v"(p_) : "v"(gzu[mi]), "v"(wr_.z));                     \
                asm("v_pk_fma_f16 %0, %1, %2, %0"                               \
                    : "+v"(p_) : "v"(gwu[mi]), "v"(wr_.w));                     \
                asm("v_pk_max_f16 %0, %0, %1"                                   \
                    : "+v"(p_) : "v"(zero_u));                                  \
                pm_[mi][c_] = p_;                                               \
            }                                                                   \
        }                                                                       \
        _Pragma("unroll")                                                       \
        for (int mi = 0; mi < 4; ++mi) {                                        \
            uint4 t_;                                                           \
            t_.x = pm_[mi][0]; t_.y = pm_[mi][1];                               \
            t_.z = pm_[mi][2]; t_.w = pm_[mi][3];                               \
            FA[mi] = __builtin_bit_cast(f16x8, t_);                             \
        } } while (0)

    // 6 global_load_dwordx4: B frags straight to VGPR (L1/L2-hit)
    #define LOADB(kk, FB) do {                                                  \
        const char* sb_ = srcB + (size_t)(kk) * BTILE;                          \
        _Pragma("unroll")                                                       \
        for (int ni = 0; ni < 6; ++ni)                                          \
            FB[ni] = *reinterpret_cast<const f16x8*>(sb_ + offB[ni]);           \
        } while (0)

    #define MFMA24(FA, FB) do {                                                 \
        _Pragma("unroll")                                                       \
        for (int mi = 0; mi < 4; ++mi)                                          \
            _Pragma("unroll")                                                   \
            for (int ni = 0; ni < 6; ++ni)                                      \
                acc[mi][ni] = __builtin_amdgcn_mfma_f32_16x16x32_f16(           \
                    FA[mi], FB[ni], acc[mi][ni], 0, 0, 0);                      \
        } while (0)

    // prologue: tiles 0,1 into regs (compiler orders via deps)
    LOADB(0, fb0); AGEN(0, fa0);
    LOADB(1, fb1); AGEN(1, fa1);

    for (int p = 0; p < KT2 / 2 - 1; ++p) {          // k = 0..93
        MFMA24(fa0, fb0);
        LOADB(2 * p + 2, fb0);
        AGEN(2 * p + 2, fa0);
        MFMA24(fa1, fb1);
        LOADB(2 * p + 3, fb1);
        AGEN(2 * p + 3, fa1);
    }
    MFMA24(fa0, fb0);                                // k = 94
    MFMA24(fa1, fb1);                                // k = 95

    #undef AGEN
    #undef LOADB
    #undef MFMA24

    // epilogue (C/D: col=lane&15, row=(lane>>4)*4+r)
    #pragma unroll
    for (int ni = 0; ni < 6; ++ni) {
        const int col = n0 + wcn * 96 + ni * 16 + fr;
        const float bias = b2[col];
        #pragma unroll
        for (int mi = 0; mi < 4; ++mi) {
            #pragma unroll
            for (int rr = 0; rr < 4; ++rr) {
                const int ro = m0 + wrm * 64 + mi * 16 + fg * 4 + rr;
                out[(size_t)ro * E_DIM + col] = acc[mi][ni][rr] + bias;
            }
        }
    }
}

// ------------------------------------------- fallback: round-1 fused ------
__global__ __launch_bounds__(256, 2)
void ffq_fused(const float* __restrict__ x, const float* __restrict__ theta,
               const float* __restrict__ W1, const float* __restrict__ b1,
               const float* __restrict__ W2, const float* __restrict__ b2,
               float* __restrict__ out)
{
    __shared__ bf16_t Asm[BM][BK];
    __shared__ bf16_t Bsm[BN][BK];
    __shared__ float  gsm[BM][4];
    __shared__ float  b2sm[BN];

    const int t = threadIdx.x;
    const int lane = t & 63, wid = t >> 6;
    const int bid = blockIdx.x;
    const int swz = (bid & 7) * (MT * NT / 8) + (bid >> 3);
    const int ntile = swz / MT, mtile = swz % MT;
    const int m0 = mtile * BM, n0 = ntile * BN;

    const float c0 = cosf(theta[0]), c1 = cosf(theta[1]);
    const float c2 = cosf(theta[2]), c3 = cosf(theta[3]);
    if (t < BM) {
        const float4 xv = *reinterpret_cast<const float4*>(x + (size_t)(m0 + t) * E_DIM);
        gsm[t][0] = cosf(xv.x) * c0; gsm[t][1] = cosf(xv.y) * c1;
        gsm[t][2] = cosf(xv.z) * c2; gsm[t][3] = cosf(xv.w) * c3;
    } else {
        const int n = t - 128;
        b2sm[n] = b2[n0 + n];
    }
    __syncthreads();

    const int rg = t >> 3, kg = t & 7;
    const int nB = t & 127, kh = t >> 7;
    const int wr = wid >> 1, wc = wid & 1;
    const int fr = lane & 15, fg = lane >> 4;

    f32x4 acc[4][4] = {};

    for (int k0 = 0; k0 < F_DIM; k0 += BK) {
        {
            const int kA = k0 + (kg << 3);
            float w1v[4][8], b1v[8];
            #pragma unroll
            for (int q = 0; q < 4; ++q) {
                const float4 lo = *reinterpret_cast<const float4*>(&W1[q * F_DIM + kA]);
                const float4 hi = *reinterpret_cast<const float4*>(&W1[q * F_DIM + kA + 4]);
                w1v[q][0] = lo.x; w1v[q][1] = lo.y; w1v[q][2] = lo.z; w1v[q][3] = lo.w;
                w1v[q][4] = hi.x; w1v[q][5] = hi.y; w1v[q][6] = hi.z; w1v[q][7] = hi.w;
            }
            {
                const float4 lo = *reinterpret_cast<const float4*>(&b1[kA]);
                const float4 hi = *reinterpret_cast<const float4*>(&b1[kA + 4]);
                b1v[0] = lo.x; b1v[1] = lo.y; b1v[2] = lo.z; b1v[3] = lo.w;
                b1v[4] = hi.x; b1v[5] = hi.y; b1v[6] = hi.z; b1v[7] = hi.w;
            }
            #pragma unroll
            for (int r = 0; r < 4; ++r) {
                const int row = (rg << 2) + r;
                const float4 g = *reinterpret_cast<const float4*>(&gsm[row][0]);
                bf16x8 v;
                #pragma unroll
                for (int kk = 0; kk < 8; ++kk) {
                    float p = b1v[kk];
                    p = fmaf(g.x, w1v[0][kk], p);
                    p = fmaf(g.y, w1v[1][kk], p);
                    p = fmaf(g.z, w1v[2][kk], p);
                    p = fmaf(g.w, w1v[3][kk], p);
                    v[kk] = (bf16_t)fmaxf(p, 0.0f);
                }
                *reinterpret_cast<bf16x8*>(&Asm[row][(kg ^ (row & 7)) << 3]) = v;
            }
        }
        {
            const float* w2p = W2 + (size_t)(k0 + (kh << 5)) * E_DIM + n0 + nB;
            float bv[32];
            #pragma unroll
            for (int kk = 0; kk < 32; ++kk) bv[kk] = w2p[kk * E_DIM];
            #pragma unroll
            for (int o = 0; o < 4; ++o) {
                bf16x8 v;
                #pragma unroll
                for (int j = 0; j < 8; ++j) v[j] = (bf16_t)bv[(o << 3) + j];
                *reinterpret_cast<bf16x8*>(&Bsm[nB][(((kh << 2) + o) ^ (nB & 7)) << 3]) = v;
            }
        }
        __syncthreads();
        #pragma unroll
        for (int ks = 0; ks < 2; ++ks) {
            const int kob = (ks << 2) + fg;
            bf16x8 af[4], bfr[4];
            #pragma unroll
            for (int mi = 0; mi < 4; ++mi) {
                const int row = (wr << 6) + (mi << 4) + fr;
                af[mi] = *reinterpret_cast<const bf16x8*>(&Asm[row][(kob ^ (row & 7)) << 3]);
            }
            #pragma unroll
            for (int ni = 0; ni < 4; ++ni) {
                const int rn = (wc << 6) + (ni << 4) + fr;
                bfr[ni] = *reinterpret_cast<const bf16x8*>(&Bsm[rn][(kob ^ (rn & 7)) << 3]);
            }
            #pragma unroll
            for (int mi = 0; mi < 4; ++mi)
                #pragma unroll
                for (int ni = 0; ni < 4; ++ni)
                    acc[mi][ni] = __builtin_amdgcn_mfma_f32_16x16x32_bf16(
                        af[mi], bfr[ni], acc[mi][ni], 0, 0, 0);
        }
        __syncthreads();
    }

    #pragma unroll
    for (int mi = 0; mi < 4; ++mi)
        #pragma unroll
        for (int ni = 0; ni < 4; ++ni) {
            const int col  = n0 + (wc << 6) + (ni << 4) + fr;
            const float bias = b2sm[(wc << 6) + (ni << 4) + fr];
            #pragma unroll
            for (int r = 0; r < 4; ++r) {
                const int row = m0 + (wr << 6) + (mi << 4) + (fg << 2) + r;
                out[(size_t)row * E_DIM + col] = acc[mi][ni][r] + bias;
            }
        }
}

// -------------------------------------------------------------- launch ----
extern "C" void kernel_launch(void* const* d_in, const int* in_sizes, int n_in,
                              void* d_out, int out_size, void* d_ws, size_t ws_size,
                              hipStream_t stream) {
    const float* x     = (const float*)d_in[0];
    const float* theta = (const float*)d_in[1];
    const float* W1    = (const float*)d_in[2];
    const float* b1    = (const float*)d_in[3];
    const float* W2    = (const float*)d_in[4];
    const float* b2    = (const float*)d_in[5];
    float* out = (float*)d_out;

    if (ws_size >= WS_NEED) {
        hipLaunchKernelGGL(ffq_prep, dim3(256), dim3(256), 0, stream,
                           x, theta, W2, (char*)d_ws);
        hipLaunchKernelGGL(ffq_gemm, dim3(256), dim3(512), 0, stream,
                           (const char*)d_ws, W1, b1, b2, out);
    } else {
        hipLaunchKernelGGL(ffq_fused, dim3(MT * NT), dim3(256), 0, stream,
                           x, theta, W1, b1, W2, b2, out);
    }
}